// Round 1
// baseline (88.029 us; speedup 1.0000x reference)
//
#include <hip/hip_runtime.h>
#include <cstdint>
#include <cmath>

#define HIDDEN   768
#define MAX_POSN 5000
#define SEQ_N    4096
#define LN_EPS   1e-12f

// ---------------------------------------------------------------------------
// Kernel 1: build the sinusoidal PE table (MAX_POSN x HIDDEN, f32) in d_ws.
// pe[pos, 2i]   = sin(pos * exp(-(2i) * ln(10000)/HIDDEN))
// pe[pos, 2i+1] = cos(pos * exp(-(2i) * ln(10000)/HIDDEN))
// 5000*384 = 1.92M sin/cos pairs -> a few microseconds; use precise sinf/cosf
// (args reach ~5000 rad; __sincosf range reduction is not trustworthy there).
// ---------------------------------------------------------------------------
__global__ __launch_bounds__(256) void pe_table_kernel(float* __restrict__ pe) {
    const int total = MAX_POSN * (HIDDEN / 2);
    int idx = blockIdx.x * blockDim.x + threadIdx.x;
    if (idx >= total) return;
    int pos = idx / (HIDDEN / 2);
    int i   = idx % (HIDDEN / 2);
    const float L = logf(10000.0f) / (float)HIDDEN;   // compile-time folded
    float div = expf(-2.0f * (float)i * L);
    float ang = (float)pos * div;
    float s, c;
    sincosf(ang, &s, &c);
    float* row = pe + (size_t)pos * HIDDEN;
    row[2 * i]     = s;
    row[2 * i + 1] = c;
}

// ---------------------------------------------------------------------------
// Kernel 2: fused embedding-sum + LayerNorm.
// One 64-lane wave per token; lane owns 3 float4 chunks (d4 = lane + 64k),
// so every row read is a fully-coalesced stream of float4s.
// USE_TABLE=false fallback computes the 4 PE rows' trig inline (only used if
// ws_size is too small for the table).
// ---------------------------------------------------------------------------
template <bool USE_TABLE>
__global__ __launch_bounds__(256) void emb_ln_kernel(
    const int*   __restrict__ ids,       // (B*N)
    const int*   __restrict__ svec,      // (B*N, 3)
    const int*   __restrict__ tt,        // (B*N)
    const float* __restrict__ word_emb,  // (VOCAB, HIDDEN)
    const float* __restrict__ type_emb,  // (2, HIDDEN)
    const float* __restrict__ gamma,     // (HIDDEN)
    const float* __restrict__ beta,      // (HIDDEN)
    const float* __restrict__ pe,        // (MAX_POSN, HIDDEN) or nullptr
    float*       __restrict__ out,       // (B*N, HIDDEN)
    int n_tokens)
{
    const int wave = threadIdx.x >> 6;
    const int lane = threadIdx.x & 63;
    const int tok  = blockIdx.x * 4 + wave;
    if (tok >= n_tokens) return;

    const int n  = tok & (SEQ_N - 1);     // position within sequence
    const int id = ids[tok];
    const int ty = tt[tok];
    const int p0 = svec[tok * 3 + 0];
    const int p1 = svec[tok * 3 + 1];
    const int p2 = svec[tok * 3 + 2];

    const float4* wrow = reinterpret_cast<const float4*>(word_emb + (size_t)id * HIDDEN);
    const float4* trow = reinterpret_cast<const float4*>(type_emb + (size_t)ty * HIDDEN);
    const float4* pn = nullptr, *q0 = nullptr, *q1 = nullptr, *q2 = nullptr;
    if (USE_TABLE) {
        pn = reinterpret_cast<const float4*>(pe + (size_t)n  * HIDDEN);
        q0 = reinterpret_cast<const float4*>(pe + (size_t)p0 * HIDDEN);
        q1 = reinterpret_cast<const float4*>(pe + (size_t)p1 * HIDDEN);
        q2 = reinterpret_cast<const float4*>(pe + (size_t)p2 * HIDDEN);
    }

    float4 acc[3];
    float s = 0.0f, ss = 0.0f;

    #pragma unroll
    for (int k = 0; k < 3; ++k) {
        const int d4 = lane + 64 * k;
        float4 x = wrow[d4];
        float4 t = trow[d4];
        x.x += t.x; x.y += t.y; x.z += t.z; x.w += t.w;
        if (USE_TABLE) {
            float4 a = pn[d4], b = q0[d4], c = q1[d4], d = q2[d4];
            x.x += a.x + b.x + c.x + d.x;
            x.y += a.y + b.y + c.y + d.y;
            x.z += a.z + b.z + c.z + d.z;
            x.w += a.w + b.w + c.w + d.w;
        } else {
            const float L = logf(10000.0f) / (float)HIDDEN;
            const int i0 = 2 * d4;        // pair index for dims 4*d4, 4*d4+1
            const int i1 = 2 * d4 + 1;    // pair index for dims 4*d4+2, 4*d4+3
            const float div0 = expf(-2.0f * (float)i0 * L);
            const float div1 = expf(-2.0f * (float)i1 * L);
            const int poss[4] = { n, p0, p1, p2 };
            #pragma unroll
            for (int r = 0; r < 4; ++r) {
                float s0, c0, s1, c1;
                sincosf((float)poss[r] * div0, &s0, &c0);
                sincosf((float)poss[r] * div1, &s1, &c1);
                x.x += s0; x.y += c0; x.z += s1; x.w += c1;
            }
        }
        acc[k] = x;
        s  += x.x + x.y + x.z + x.w;
        ss += x.x * x.x + x.y * x.y + x.z * x.z + x.w * x.w;
    }

    // 64-lane butterfly reduction: every lane ends with the full sums.
    #pragma unroll
    for (int off = 1; off < 64; off <<= 1) {
        s  += __shfl_xor(s,  off);
        ss += __shfl_xor(ss, off);
    }

    const float mean = s * (1.0f / (float)HIDDEN);
    const float var  = ss * (1.0f / (float)HIDDEN) - mean * mean;
    const float inv  = rsqrtf(var + LN_EPS);

    const float4* g4 = reinterpret_cast<const float4*>(gamma);
    const float4* b4 = reinterpret_cast<const float4*>(beta);
    float4* orow = reinterpret_cast<float4*>(out + (size_t)tok * HIDDEN);

    #pragma unroll
    for (int k = 0; k < 3; ++k) {
        const int d4 = lane + 64 * k;
        const float4 g = g4[d4];
        const float4 b = b4[d4];
        const float4 x = acc[k];
        float4 r;
        r.x = (x.x - mean) * inv * g.x + b.x;
        r.y = (x.y - mean) * inv * g.y + b.y;
        r.z = (x.z - mean) * inv * g.z + b.z;
        r.w = (x.w - mean) * inv * g.w + b.w;
        orow[d4] = r;
    }
}

extern "C" void kernel_launch(void* const* d_in, const int* in_sizes, int n_in,
                              void* d_out, int out_size, void* d_ws, size_t ws_size,
                              hipStream_t stream) {
    const int*   ids      = (const int*)d_in[0];   // input_ids      (B*N)
    const int*   svec     = (const int*)d_in[1];   // tok_struct_vec (B*N*3)
    const int*   tt       = (const int*)d_in[2];   // token_type_ids (B*N)
    const float* word_emb = (const float*)d_in[3]; // (VOCAB, HIDDEN)
    const float* type_emb = (const float*)d_in[4]; // (2, HIDDEN)
    const float* gamma    = (const float*)d_in[5]; // (HIDDEN)
    const float* beta     = (const float*)d_in[6]; // (HIDDEN)
    float*       out      = (float*)d_out;

    const int n_tokens = in_sizes[0];
    const int grid_main = (n_tokens + 3) / 4;      // 4 tokens (waves) per block

    const size_t pe_bytes = (size_t)MAX_POSN * HIDDEN * sizeof(float);
    if (ws_size >= pe_bytes) {
        float* pe = (float*)d_ws;
        const int total_pairs = MAX_POSN * (HIDDEN / 2);
        pe_table_kernel<<<(total_pairs + 255) / 256, 256, 0, stream>>>(pe);
        emb_ln_kernel<true><<<grid_main, 256, 0, stream>>>(
            ids, svec, tt, word_emb, type_emb, gamma, beta, pe, out, n_tokens);
    } else {
        emb_ln_kernel<false><<<grid_main, 256, 0, stream>>>(
            ids, svec, tt, word_emb, type_emb, gamma, beta, nullptr, out, n_tokens);
    }
}

// Round 2
// 57.921 us; speedup vs baseline: 1.5198x; 1.5198x over previous
//
#include <hip/hip_runtime.h>
#include <cstdint>
#include <cmath>

#define HIDDEN   768
#define NPAIR    (HIDDEN / 2)      // 384 (sin,cos) pairs per row
#define MAX_POSN 5000
#define SEQ_N    4096
#define LN_EPS   1e-12f
#define N_HI     80                // ceil(5000/64) rows: angle = 64*hi*d_i
#define N_LO     64                // angle = lo*d_i

// ---------------------------------------------------------------------------
// Kernel 1: build the two compact angle-addition tables in d_ws.
//   T1[hi][i] = (sin, cos)(64*hi * d_i)   hi in [0,80)
//   T2[lo][i] = (sin, cos)(lo    * d_i)   lo in [0,64)
// with d_i = exp(-2i * ln(10000)/HIDDEN), i in [0,384).
// pe[p][2i] = sin(p*d_i), pe[p][2i+1] = cos(p*d_i), p = 64*hi + lo,
// reconstructed exactly via sin(A+B), cos(A+B).
// Total 144*384 = 55296 sincos -> ~1 us. Tables = 442 KB -> L2-resident.
// ---------------------------------------------------------------------------
__global__ __launch_bounds__(256) void pe_tables_kernel(float2* __restrict__ t1,
                                                        float2* __restrict__ t2) {
    const int total = (N_HI + N_LO) * NPAIR;
    int idx = blockIdx.x * blockDim.x + threadIdx.x;
    if (idx >= total) return;
    int r = idx / NPAIR;
    int i = idx % NPAIR;
    const float L = logf(10000.0f) / (float)HIDDEN;
    float div = expf(-2.0f * (float)i * L);
    float s, c;
    if (r < N_HI) {
        sincosf((float)(r * 64) * div, &s, &c);
        t1[(size_t)r * NPAIR + i] = make_float2(s, c);
    } else {
        int lo = r - N_HI;
        sincosf((float)lo * div, &s, &c);
        t2[(size_t)lo * NPAIR + i] = make_float2(s, c);
    }
}

// ---------------------------------------------------------------------------
// Kernel 2: fused embedding-sum + LayerNorm, PE rows reconstructed from the
// L2-resident tables. One 64-lane wave per token; lane owns 3 float4 output
// chunks (dims 4*d4..4*d4+3 == pair indices 2*d4, 2*d4+1), so a float4 load
// from a (sin,cos)-interleaved table row delivers exactly the two pairs.
// ---------------------------------------------------------------------------
__global__ __launch_bounds__(256) void emb_ln_kernel(
    const int*    __restrict__ ids,       // (B*N)
    const int*    __restrict__ svec,      // (B*N, 3)
    const int*    __restrict__ tt,        // (B*N)
    const float*  __restrict__ word_emb,  // (VOCAB, HIDDEN)
    const float*  __restrict__ type_emb,  // (2, HIDDEN)
    const float*  __restrict__ gamma,     // (HIDDEN)
    const float*  __restrict__ beta,      // (HIDDEN)
    const float2* __restrict__ t1,        // (N_HI, NPAIR) (sin,cos)
    const float2* __restrict__ t2,        // (N_LO, NPAIR) (sin,cos)
    float*        __restrict__ out,       // (B*N, HIDDEN)
    int n_tokens)
{
    const int wave = threadIdx.x >> 6;
    const int lane = threadIdx.x & 63;
    const int tok  = blockIdx.x * 4 + wave;
    if (tok >= n_tokens) return;

    const int n  = tok & (SEQ_N - 1);     // position within sequence
    const int id = ids[tok];
    const int ty = tt[tok];
    const int p0 = svec[tok * 3 + 0];
    const int p1 = svec[tok * 3 + 1];
    const int p2 = svec[tok * 3 + 2];

    const float4* wrow = reinterpret_cast<const float4*>(word_emb + (size_t)id * HIDDEN);
    const float4* trow = reinterpret_cast<const float4*>(type_emb + (size_t)ty * HIDDEN);

    // Table row pointers for the 4 PE positions (hi row in T1, lo row in T2).
    const float4* A0 = reinterpret_cast<const float4*>(t1 + (size_t)(n  >> 6) * NPAIR);
    const float4* B0 = reinterpret_cast<const float4*>(t2 + (size_t)(n  & 63) * NPAIR);
    const float4* A1 = reinterpret_cast<const float4*>(t1 + (size_t)(p0 >> 6) * NPAIR);
    const float4* B1 = reinterpret_cast<const float4*>(t2 + (size_t)(p0 & 63) * NPAIR);
    const float4* A2 = reinterpret_cast<const float4*>(t1 + (size_t)(p1 >> 6) * NPAIR);
    const float4* B2 = reinterpret_cast<const float4*>(t2 + (size_t)(p1 & 63) * NPAIR);
    const float4* A3 = reinterpret_cast<const float4*>(t1 + (size_t)(p2 >> 6) * NPAIR);
    const float4* B3 = reinterpret_cast<const float4*>(t2 + (size_t)(p2 & 63) * NPAIR);

    float4 acc[3];
    float s = 0.0f, ss = 0.0f;

    #pragma unroll
    for (int k = 0; k < 3; ++k) {
        const int d4 = lane + 64 * k;
        float4 w = wrow[d4];
        float4 t = trow[d4];
        float4 x;
        x.x = w.x + t.x; x.y = w.y + t.y; x.z = w.z + t.z; x.w = w.w + t.w;

        // a = (sinA0, cosA0, sinA1, cosA1), b = (sinB0, cosB0, sinB1, cosB1)
        // sin(A+B) = sA*cB + cA*sB ; cos(A+B) = cA*cB - sA*sB
        {
            float4 a = A0[d4], b = B0[d4];
            x.x += a.x * b.y + a.y * b.x;  x.y += a.y * b.y - a.x * b.x;
            x.z += a.z * b.w + a.w * b.z;  x.w += a.w * b.w - a.z * b.z;
        }
        {
            float4 a = A1[d4], b = B1[d4];
            x.x += a.x * b.y + a.y * b.x;  x.y += a.y * b.y - a.x * b.x;
            x.z += a.z * b.w + a.w * b.z;  x.w += a.w * b.w - a.z * b.z;
        }
        {
            float4 a = A2[d4], b = B2[d4];
            x.x += a.x * b.y + a.y * b.x;  x.y += a.y * b.y - a.x * b.x;
            x.z += a.z * b.w + a.w * b.z;  x.w += a.w * b.w - a.z * b.z;
        }
        {
            float4 a = A3[d4], b = B3[d4];
            x.x += a.x * b.y + a.y * b.x;  x.y += a.y * b.y - a.x * b.x;
            x.z += a.z * b.w + a.w * b.z;  x.w += a.w * b.w - a.z * b.z;
        }

        acc[k] = x;
        s  += x.x + x.y + x.z + x.w;
        ss += x.x * x.x + x.y * x.y + x.z * x.z + x.w * x.w;
    }

    // 64-lane butterfly reduction: every lane ends with the full sums.
    #pragma unroll
    for (int off = 1; off < 64; off <<= 1) {
        s  += __shfl_xor(s,  off);
        ss += __shfl_xor(ss, off);
    }

    const float mean = s * (1.0f / (float)HIDDEN);
    const float var  = ss * (1.0f / (float)HIDDEN) - mean * mean;
    const float inv  = rsqrtf(var + LN_EPS);

    const float4* g4 = reinterpret_cast<const float4*>(gamma);
    const float4* b4 = reinterpret_cast<const float4*>(beta);
    float4* orow = reinterpret_cast<float4*>(out + (size_t)tok * HIDDEN);

    #pragma unroll
    for (int k = 0; k < 3; ++k) {
        const int d4 = lane + 64 * k;
        const float4 g = g4[d4];
        const float4 b = b4[d4];
        const float4 x = acc[k];
        float4 r;
        r.x = (x.x - mean) * inv * g.x + b.x;
        r.y = (x.y - mean) * inv * g.y + b.y;
        r.z = (x.z - mean) * inv * g.z + b.z;
        r.w = (x.w - mean) * inv * g.w + b.w;
        orow[d4] = r;
    }
}

extern "C" void kernel_launch(void* const* d_in, const int* in_sizes, int n_in,
                              void* d_out, int out_size, void* d_ws, size_t ws_size,
                              hipStream_t stream) {
    const int*   ids      = (const int*)d_in[0];   // input_ids      (B*N)
    const int*   svec     = (const int*)d_in[1];   // tok_struct_vec (B*N*3)
    const int*   tt       = (const int*)d_in[2];   // token_type_ids (B*N)
    const float* word_emb = (const float*)d_in[3]; // (VOCAB, HIDDEN)
    const float* type_emb = (const float*)d_in[4]; // (2, HIDDEN)
    const float* gamma    = (const float*)d_in[5]; // (HIDDEN)
    const float* beta     = (const float*)d_in[6]; // (HIDDEN)
    float*       out      = (float*)d_out;

    const int n_tokens = in_sizes[0];
    const int grid_main = (n_tokens + 3) / 4;      // 4 tokens (waves) per block

    // Workspace layout: T1 (80x384 float2) | T2 (64x384 float2) = 442 KB.
    // (Prior round proved ws_size >= 15 MB, so this always fits.)
    float2* t1 = (float2*)d_ws;
    float2* t2 = t1 + (size_t)N_HI * NPAIR;

    const int total_tab = (N_HI + N_LO) * NPAIR;
    pe_tables_kernel<<<(total_tab + 255) / 256, 256, 0, stream>>>(t1, t2);
    emb_ln_kernel<<<grid_main, 256, 0, stream>>>(
        ids, svec, tt, word_emb, type_emb, gamma, beta, t1, t2, out, n_tokens);
}